// Round 4
// baseline (1999.718 us; speedup 1.0000x reference)
//
#include <hip/hip_runtime.h>

#define NB   16
#define NPT  4096
#define CINF 64
#define COUTF 128
#define MC   1024
#define KG   64
#define PTOT (NB*KG*MC)   /* 1048576 */

typedef unsigned short u16;
typedef unsigned int   u32;
typedef unsigned long long u64;

static __device__ __forceinline__ float blv(u16 v){ return __uint_as_float(((u32)v) << 16); }
static __device__ __forceinline__ u16 f2b(float f){
  u32 x = __float_as_uint(f);
  return (u16)((x + 0x7fffu + ((x >> 16) & 1u)) >> 16);
}

template<bool BF> struct io;
template<> struct io<true>{
  static __device__ __forceinline__ float ld(const void* p, size_t i){ return blv(((const u16*)p)[i]); }
  static __device__ __forceinline__ void st(void* p, size_t i, float v){ ((u16*)p)[i] = f2b(v); }
};
template<> struct io<false>{
  static __device__ __forceinline__ float ld(const void* p, size_t i){ return ((const float*)p)[i]; }
  static __device__ __forceinline__ void st(void* p, size_t i, float v){ ((float*)p)[i] = v; }
};

// weight LDS accessors: BF stores raw u16 (exact), F32 stores f32
template<bool BF>
static __device__ __forceinline__ float4 ldw4(const void* w, int idx){
  if constexpr (BF) {
    ushort4 u = *(const ushort4*)((const u16*)w + idx);
    return make_float4(blv(u.x), blv(u.y), blv(u.z), blv(u.w));
  } else return *(const float4*)((const float*)w + idx);
}
template<bool BF>
static __device__ __forceinline__ void ldw8(const void* w, int idx, float4& a, float4& b){
  if constexpr (BF) {
    ushort4 u0 = *(const ushort4*)((const u16*)w + idx);
    ushort4 u1 = *(const ushort4*)((const u16*)w + idx + 4);
    a = make_float4(blv(u0.x), blv(u0.y), blv(u0.z), blv(u0.w));
    b = make_float4(blv(u1.x), blv(u1.y), blv(u1.z), blv(u1.w));
  } else {
    a = *(const float4*)((const float*)w + idx);
    b = *(const float4*)((const float*)w + idx + 4);
  }
}

// ---------------------------------------------------------------- dtype detector + stats zero
__global__ __launch_bounds__(256) void detect_kernel(const void* pts, int* flagp, double* dstats)
{
  const int t = threadIdx.x;
  if (t < 64) {
    u32 w = ((const u32*)pts)[t];
    u64 m = __ballot((w & 0xFFFFu) < 0x4000u);
    if (t == 0) *flagp = (m == ~0ull) ? 1 : 0;
  }
  dstats[t] = 0.0;
}

// ---------------------------------------------------------------- FPS
template<bool BF>
static __device__ void fps_body(const void* pts, float* __restrict__ centw, void* out,
                                float* lx, float* ly, float* lz, u64 (*red)[4])
{
  const int t = threadIdx.x, b = blockIdx.x;
  const size_t pbase = (size_t)b*3*NPT;
  for (int i = t; i < NPT; i += 256) {
    lx[i] = io<BF>::ld(pts, pbase + i);
    ly[i] = io<BF>::ld(pts, pbase + NPT + i);
    lz[i] = io<BF>::ld(pts, pbase + 2*NPT + i);
  }
  __syncthreads();
  float qx[16],qy[16],qz[16],dd[16];
  const int base = t*16;
  #pragma unroll
  for (int j=0;j<16;++j){ qx[j]=lx[base+j]; qy[j]=ly[base+j]; qz[j]=lz[base+j]; dd[j]=1e10f; }
  int last = 0;
  const int lane = t & 63, wv = t >> 6;
  for (int it = 0; it < MC; ++it) {
    float cx = lx[last], cy = ly[last], cz = lz[last];
    if (t < 3) {
      float v = (t==0)?cx:((t==1)?cy:cz);
      centw[((size_t)b*MC + it)*3 + t] = v;
      io<BF>::st(out, (size_t)b*3*MC + (size_t)it*3 + t, v);
    }
    float bv = -1.f; int bi = base;
    #pragma unroll
    for (int j=0;j<16;++j) {
      float dx = __fsub_rn(qx[j], cx);
      float dy = __fsub_rn(qy[j], cy);
      float dz = __fsub_rn(qz[j], cz);
      float d  = __fadd_rn(__fadd_rn(__fmul_rn(dx,dx), __fmul_rn(dy,dy)), __fmul_rn(dz,dz));
      float nd = fminf(dd[j], d);
      dd[j] = nd;
      if (nd > bv) { bv = nd; bi = base + j; }
    }
    u64 key = ((u64)__float_as_uint(bv) << 32) | (u32)(~bi);
    #pragma unroll
    for (int off = 32; off > 0; off >>= 1) {
      u64 o = __shfl_xor(key, off, 64);
      if (o > key) key = o;
    }
    if (lane == 0) red[it & 1][wv] = key;
    __syncthreads();
    u64 k0 = red[it&1][0], k1 = red[it&1][1];
    u64 k2 = red[it&1][2], k3 = red[it&1][3];
    if (k1 > k0) k0 = k1;
    if (k3 > k2) k2 = k3;
    if (k2 > k0) k0 = k2;
    last = (int)(~(u32)k0);
  }
}

__global__ __launch_bounds__(256) void fps_kernel(const void* pts, float* centw, void* out,
                                                  const int* flagp)
{
  __shared__ float lx[NPT], ly[NPT], lz[NPT];
  __shared__ u64 red[2][4];
  if (*flagp) fps_body<true >(pts, centw, out, lx, ly, lz, red);
  else        fps_body<false>(pts, centw, out, lx, ly, lz, red);
}

// ---------------------------------------------------------------- ball query
template<bool BF>
static __device__ void ballq_body(const void* pts, const float* __restrict__ centw,
                                  int* __restrict__ gidx)
{
  const int lane = threadIdx.x & 63;
  const int g = blockIdx.x*4 + (threadIdx.x >> 6);
  const int b = g >> 10;
  const size_t pbase = (size_t)b*3*NPT;
  const float cx = centw[(size_t)g*3+0], cy = centw[(size_t)g*3+1], cz = centw[(size_t)g*3+2];
  int* gout = gidx + (size_t)g*KG;
  int taken = 0, idx0 = 0;
  for (int s = 0; s < NPT; s += 64) {
    int n = s + lane;
    float dx = __fsub_rn(cx, io<BF>::ld(pts, pbase + n));
    float dy = __fsub_rn(cy, io<BF>::ld(pts, pbase + NPT + n));
    float dz = __fsub_rn(cz, io<BF>::ld(pts, pbase + 2*NPT + n));
    float d2 = __fadd_rn(__fadd_rn(__fmul_rn(dx,dx), __fmul_rn(dy,dy)), __fmul_rn(dz,dz));
    u64 mask = __ballot(d2 <= 0.04f);
    if (mask) {
      if (taken == 0) idx0 = s + __ffsll((long long)mask) - 1;
      bool win = (mask >> lane) & 1;
      int pos = taken + __popcll(mask & ((1ull << lane) - 1ull));
      if (win && pos < KG) gout[pos] = n;
      taken += (int)__popcll(mask);
      if (taken >= KG) break;
    }
  }
  int cnt = taken < KG ? taken : KG;
  if (lane >= cnt) gout[lane] = idx0;
}

__global__ __launch_bounds__(256) void ballq_kernel(const void* pts, const float* centw,
                                                    int* gidx, const int* flagp)
{
  if (*flagp) ballq_body<true >(pts, centw, gidx);
  else        ballq_body<false>(pts, centw, gidx);
}

// ---------------------------------------------------------------- features [B,C,N] -> f32 [B,N,C]
template<bool BF>
static __device__ void transpose_body(const void* feats, float* __restrict__ ftp)
{
  const int idx = blockIdx.x*256 + threadIdx.x;
  const int b = idx >> 12, n = idx & (NPT-1);
  const size_t base = (size_t)b*CINF*NPT + n;
  float* o = ftp + (size_t)idx*CINF;
  #pragma unroll
  for (int c = 0; c < CINF; c += 4) {
    float4 v;
    v.x = io<BF>::ld(feats, base + (size_t)(c+0)*NPT);
    v.y = io<BF>::ld(feats, base + (size_t)(c+1)*NPT);
    v.z = io<BF>::ld(feats, base + (size_t)(c+2)*NPT);
    v.w = io<BF>::ld(feats, base + (size_t)(c+3)*NPT);
    *(float4*)(o + c) = v;
  }
}

__global__ __launch_bounds__(256) void transpose_kernel(const void* feats, float* ftp,
                                                        const int* flagp)
{
  if (*flagp) transpose_body<true >(feats, ftp);
  else        transpose_body<false>(feats, ftp);
}

// ---------------------------------------------------------------- MLP passes (register-blocked)
// X layout per group: x[k][c'] stride 68, c' 0..63 = features, 64..66 = rel coords, 67 = pad.
// Per-thread tile: 4k x 4co (conv1/conv2), 4k x 8co (conv3).
// BF variant stores weights in LDS as raw u16 (exact bf16) -> stage3 fits 2 blocks/CU.
template<int STAGE, bool BF>
__global__ __launch_bounds__(256) void mlp_kernel(
    const void* pts, const void* feats, const float* __restrict__ ftp, int ft,
    const void* w1p, const void* b1p, const void* w2p, const void* b2p,
    const void* w3p, const void* b3p,
    const float* __restrict__ centw, const int* __restrict__ gidxp,
    double* __restrict__ dstats, const float* __restrict__ fstats, void* out,
    const int* __restrict__ flagp)
{
  if ((*flagp != 0) != BF) return;   // dtype-dispatch: wrong-mode kernel exits

  constexpr int ACTF = 4352 + (STAGE>=2 ? 4352 : 0);                 // floats (Xs [+ z1])
  constexpr int W1B  = BF ? 4352*2 : 4352*4;
  constexpr int W2B  = (STAGE>=2) ? (BF ? 4096*2 : 4096*4) : 0;
  constexpr int W3B  = (STAGE==3) ? (BF ? 8192*2 : 8192*4) : 0;
  constexpr int REDB = (STAGE==1) ? 8704 : 0;                        // stage2/3 overlay z1
  constexpr int SMB  = ACTF*4 + W1B + W2B + W3B + REDB;
  __shared__ alignas(16) unsigned char smem[SMB];
  __shared__ int gids[64];
  __shared__ float c3s[3];

  float* Xs  = (float*)smem;                       // [64][68]
  float* z1s = Xs + 4352;                          // stage>=2
  void*  w1t = smem + ACTF*4;
  void*  w2t = smem + ACTF*4 + W1B;
  void*  w3t = smem + ACTF*4 + W1B + W2B;
  float* red = (STAGE==1) ? (float*)(smem + ACTF*4 + W1B) : z1s;   // 2176 floats

  constexpr int TG = 8;
  const int t = threadIdx.x, lane = t & 63, wv = t >> 6;
  const int kq = lane >> 4, coq = lane & 15;
  const int co0 = coq * 4;
  const int co08 = coq * 8;
  const int k0  = wv*16 + kq*4;
  const int b   = blockIdx.x >> 7;
  const int m0  = (blockIdx.x & 127) * TG;

  // ---- stage weights into LDS, [c][co] layout (raw u16 copy when BF: exact)
  for (int e = t; e < 4352; e += 256) {
    int cp = e >> 6, co = e & 63;
    int src = (cp < 64) ? (co*67 + cp + 3) : (cp < 67 ? co*67 + cp - 64 : -1);
    if constexpr (BF) ((u16*)w1t)[e]  = (src >= 0) ? ((const u16*)w1p)[src]  : (u16)0;
    else              ((float*)w1t)[e] = (src >= 0) ? ((const float*)w1p)[src] : 0.f;
  }
  if constexpr (STAGE >= 2)
    for (int e = t; e < 4096; e += 256) {
      int src = (e & 63)*64 + (e >> 6);
      if constexpr (BF) ((u16*)w2t)[e] = ((const u16*)w2p)[src];
      else              ((float*)w2t)[e] = ((const float*)w2p)[src];
    }
  if constexpr (STAGE == 3)
    for (int e = t; e < 8192; e += 256) {
      int src = (e & 127)*64 + (e >> 7);
      if constexpr (BF) ((u16*)w3t)[e] = ((const u16*)w3p)[src];
      else              ((float*)w3t)[e] = ((const float*)w3p)[src];
    }

  // ---- per-thread constants
  float b1v[4], b2v[4], sc1v[4], sh1v[4], sc2v[4], sh2v[4], b3v[8];
  #pragma unroll
  for (int j=0;j<4;++j) b1v[j] = io<BF>::ld(b1p, co0+j);
  if constexpr (STAGE >= 2) {
    #pragma unroll
    for (int j=0;j<4;++j) {
      b2v[j]  = io<BF>::ld(b2p, co0+j);
      sc1v[j] = fstats[co0+j]; sh1v[j] = fstats[64+co0+j];
    }
  }
  if constexpr (STAGE == 3) {
    #pragma unroll
    for (int j=0;j<4;++j) { sc2v[j] = fstats[128+co0+j]; sh2v[j] = fstats[192+co0+j]; }
    #pragma unroll
    for (int j=0;j<8;++j) b3v[j] = io<BF>::ld(b3p, co08+j);
  }
  float run_s = 0.f, run_q = 0.f;
  float outv[8];
  __syncthreads();

  for (int mi = 0; mi < TG; ++mi) {
    const int m = m0 + mi;
    const size_t g = (size_t)b*MC + m;
    if (t < 64) gids[t] = gidxp[g*KG + t];
    if (t < 3)  c3s[t]  = centw[g*3 + t];
    __syncthreads();
    // ---- gather row k=lane; wave wv fills feature channels [wv*16, wv*16+16)
    {
      const int gi = gids[lane];
      float* xrow = Xs + lane*68;
      if (ft) {
        const float* fp = ftp + ((size_t)b*NPT + gi)*CINF + wv*16;
        float4 v0 = ((const float4*)fp)[0], v1 = ((const float4*)fp)[1];
        float4 v2 = ((const float4*)fp)[2], v3 = ((const float4*)fp)[3];
        float4* d = (float4*)(xrow + wv*16);
        d[0]=v0; d[1]=v1; d[2]=v2; d[3]=v3;
      } else {
        const int cs = wv*16;
        for (int c = cs; c < cs+16; ++c)
          xrow[c] = io<BF>::ld(feats, ((size_t)b*CINF + c)*NPT + gi);
      }
      if (wv == 0) {
        const size_t pbase = (size_t)b*3*NPT;
        xrow[64] = __fsub_rn(io<BF>::ld(pts, pbase + gi),         c3s[0]);
        xrow[65] = __fsub_rn(io<BF>::ld(pts, pbase + NPT + gi),   c3s[1]);
        xrow[66] = __fsub_rn(io<BF>::ld(pts, pbase + 2*NPT + gi), c3s[2]);
        xrow[67] = 0.f;
      }
    }
    __syncthreads();
    // ---- conv1: 4k x 4co tile per thread
    float acc[4][4];
    #pragma unroll
    for (int r=0;r<4;++r){
      #pragma unroll
      for (int j=0;j<4;++j) acc[r][j] = b1v[j];
    }
    {
      const float* xb = Xs + (size_t)k0*68;
      for (int c4 = 0; c4 < 17; ++c4) {
        float4 xv[4], wr[4];
        #pragma unroll
        for (int r=0;r<4;++r) xv[r] = *(const float4*)(xb + r*68 + c4*4);
        #pragma unroll
        for (int q=0;q<4;++q) wr[q] = ldw4<BF>(w1t, (c4*4+q)*64 + co0);
        #pragma unroll
        for (int q=0;q<4;++q){
          const float* w = (const float*)&wr[q];
          #pragma unroll
          for (int r=0;r<4;++r){
            const float x = ((const float*)&xv[r])[q];
            #pragma unroll
            for (int j=0;j<4;++j) acc[r][j] = fmaf(x, w[j], acc[r][j]);
          }
        }
      }
    }
    if constexpr (STAGE == 1) {
      #pragma unroll
      for (int j=0;j<4;++j){
        float s  = (acc[0][j]+acc[1][j]) + (acc[2][j]+acc[3][j]);
        float q2 = fmaf(acc[0][j],acc[0][j], fmaf(acc[1][j],acc[1][j],
                   fmaf(acc[2][j],acc[2][j], acc[3][j]*acc[3][j])));
        red[(co0+j)*17 + wv*4 + kq] = s;
        red[1088 + (co0+j)*17 + wv*4 + kq] = q2;
      }
      __syncthreads();
      if (t < 64) {
        const float* r1 = red + t*17; const float* r2 = red + 1088 + t*17;
        float s=0.f, q=0.f;
        #pragma unroll
        for (int i=0;i<16;++i){ s += r1[i]; q += r2[i]; }
        run_s += s; run_q += q;
      }
    } else {
      // ---- bn1+relu -> z1
      #pragma unroll
      for (int r=0;r<4;++r){
        float4 zv;
        zv.x = fmaxf(0.f, fmaf(acc[r][0], sc1v[0], sh1v[0]));
        zv.y = fmaxf(0.f, fmaf(acc[r][1], sc1v[1], sh1v[1]));
        zv.z = fmaxf(0.f, fmaf(acc[r][2], sc1v[2], sh1v[2]));
        zv.w = fmaxf(0.f, fmaf(acc[r][3], sc1v[3], sh1v[3]));
        *(float4*)(z1s + (size_t)(k0+r)*68 + co0) = zv;
      }
      __syncthreads();
      // ---- conv2
      float acc2[4][4];
      #pragma unroll
      for (int r=0;r<4;++r){
        #pragma unroll
        for (int j=0;j<4;++j) acc2[r][j] = b2v[j];
      }
      {
        const float* zb = z1s + (size_t)k0*68;
        for (int c4 = 0; c4 < 16; ++c4) {
          float4 xv[4], wr[4];
          #pragma unroll
          for (int r=0;r<4;++r) xv[r] = *(const float4*)(zb + r*68 + c4*4);
          #pragma unroll
          for (int q=0;q<4;++q) wr[q] = ldw4<BF>(w2t, (c4*4+q)*64 + co0);
          #pragma unroll
          for (int q=0;q<4;++q){
            const float* w = (const float*)&wr[q];
            #pragma unroll
            for (int r=0;r<4;++r){
              const float x = ((const float*)&xv[r])[q];
              #pragma unroll
              for (int j=0;j<4;++j) acc2[r][j] = fmaf(x, w[j], acc2[r][j]);
            }
          }
        }
      }
      if constexpr (STAGE == 2) {
        __syncthreads();   // conv2 z1-reads complete before red overlays z1
        #pragma unroll
        for (int j=0;j<4;++j){
          float s  = (acc2[0][j]+acc2[1][j]) + (acc2[2][j]+acc2[3][j]);
          float q2 = fmaf(acc2[0][j],acc2[0][j], fmaf(acc2[1][j],acc2[1][j],
                     fmaf(acc2[2][j],acc2[2][j], acc2[3][j]*acc2[3][j])));
          red[(co0+j)*17 + wv*4 + kq] = s;
          red[1088 + (co0+j)*17 + wv*4 + kq] = q2;
        }
        __syncthreads();
        if (t < 64) {
          const float* r1 = red + t*17; const float* r2 = red + 1088 + t*17;
          float s=0.f, q=0.f;
          #pragma unroll
          for (int i=0;i<16;++i){ s += r1[i]; q += r2[i]; }
          run_s += s; run_q += q;
        }
      } else {
        // ---- STAGE 3: bn2+relu -> z2 (overlays Xs; rows wave-private)
        #pragma unroll
        for (int r=0;r<4;++r){
          float4 zv;
          zv.x = fmaxf(0.f, fmaf(acc2[r][0], sc2v[0], sh2v[0]));
          zv.y = fmaxf(0.f, fmaf(acc2[r][1], sc2v[1], sh2v[1]));
          zv.z = fmaxf(0.f, fmaf(acc2[r][2], sc2v[2], sh2v[2]));
          zv.w = fmaxf(0.f, fmaf(acc2[r][3], sc2v[3], sh2v[3]));
          *(float4*)(Xs + (size_t)(k0+r)*68 + co0) = zv;
        }
        __syncthreads();   // orders: all z1-reads + z2-writes done; redm may overlay z1 after conv3
        // ---- conv3: 4k x 8co tile per thread
        float a3[4][8];
        #pragma unroll
        for (int r=0;r<4;++r){
          #pragma unroll
          for (int j=0;j<8;++j) a3[r][j] = b3v[j];
        }
        {
          const float* zb = Xs + (size_t)k0*68;
          for (int c4 = 0; c4 < 16; ++c4) {
            float4 xv[4], wr[4][2];
            #pragma unroll
            for (int r=0;r<4;++r) xv[r] = *(const float4*)(zb + r*68 + c4*4);
            #pragma unroll
            for (int q=0;q<4;++q) ldw8<BF>(w3t, (c4*4+q)*128 + co08, wr[q][0], wr[q][1]);
            #pragma unroll
            for (int q=0;q<4;++q){
              const float* w = (const float*)&wr[q][0];
              #pragma unroll
              for (int r=0;r<4;++r){
                const float x = ((const float*)&xv[r])[q];
                #pragma unroll
                for (int j=0;j<8;++j) a3[r][j] = fmaf(x, w[j], a3[r][j]);
              }
            }
          }
        }
        float* redm = red;   // overlays z1 (dead since pre-conv3 barrier)
        #pragma unroll
        for (int j=0;j<8;++j){
          float mv = fmaxf(fmaxf(a3[0][j],a3[1][j]), fmaxf(a3[2][j],a3[3][j]));
          redm[(co08+j)*17 + wv*4 + kq] = mv;
        }
        __syncthreads();
        if (t < 128) {
          const float* rr = redm + t*17;
          float s = rr[0];
          #pragma unroll
          for (int i=1;i<16;++i) s = fmaxf(s, rr[i]);
          outv[mi] = s;
        }
      }
    }
  }
  if constexpr (STAGE <= 2) {
    if (t < 64) {
      atomicAdd(&dstats[(STAGE==1 ? 0 : 128) + lane], (double)run_s);
      atomicAdd(&dstats[(STAGE==1 ? 64 : 192) + lane], (double)run_q);
    }
  } else {
    if (t < 128) {
      const size_t obase = (size_t)NB*3*MC + ((size_t)b*COUTF + t)*MC + m0;
      if (BF) {
        uint4 v;
        v.x = (u32)f2b(outv[0]) | ((u32)f2b(outv[1]) << 16);
        v.y = (u32)f2b(outv[2]) | ((u32)f2b(outv[3]) << 16);
        v.z = (u32)f2b(outv[4]) | ((u32)f2b(outv[5]) << 16);
        v.w = (u32)f2b(outv[6]) | ((u32)f2b(outv[7]) << 16);
        *(uint4*)((u16*)out + obase) = v;
      } else {
        float* op = (float*)out + obase;
        *(float4*)(op)     = make_float4(outv[0],outv[1],outv[2],outv[3]);
        *(float4*)(op + 4) = make_float4(outv[4],outv[5],outv[6],outv[7]);
      }
    }
  }
}

// ---------------------------------------------------------------- BN finalize
__global__ void finalize_kernel(const double* __restrict__ dstats, float* __restrict__ fstats,
                                const void* g, const void* beta, const int* flagp, int stage)
{
  const int t = threadIdx.x;   // 64
  const int off = (stage==1) ? 0 : 128;
  const double inv = 1.0 / (double)PTOT;
  double mu = dstats[off + t] * inv;
  double q  = dstats[off + 64 + t] * inv;
  double var = q - mu*mu;
  if (var < 0.0) var = 0.0;
  float gg, bb;
  if (*flagp) { gg = blv(((const u16*)g)[t]);  bb = blv(((const u16*)beta)[t]); }
  else        { gg = ((const float*)g)[t];     bb = ((const float*)beta)[t]; }
  double scale = (double)gg / sqrt(var + 1e-5);
  fstats[off + t]      = (float)scale;
  fstats[off + 64 + t] = bb - (float)(mu*scale);
}

// ---------------------------------------------------------------- host
extern "C" void kernel_launch(void* const* d_in, const int* in_sizes, int n_in,
                              void* d_out, int out_size, void* d_ws, size_t ws_size,
                              hipStream_t stream)
{
  (void)in_sizes; (void)n_in; (void)out_size;
  const void* pts  = d_in[0];
  const void* feats= d_in[1];
  const void* w1   = d_in[2];
  const void* b1   = d_in[3];
  const void* g1   = d_in[4];
  const void* be1  = d_in[5];
  const void* w2   = d_in[6];
  const void* b2   = d_in[7];
  const void* g2   = d_in[8];
  const void* be2  = d_in[9];
  const void* w3   = d_in[10];
  const void* b3   = d_in[11];

  char* ws = (char*)d_ws;
  int*    flag   = (int*)ws;
  double* dstats = (double*)(ws + 64);
  float*  fstats = (float*)(ws + 2112);
  float*  centw  = (float*)(ws + 4096);
  int*    gidx   = (int*)(ws + 200704);
  float*  ftp    = (float*)(ws + 4395008);
  const bool ft = ws_size >= 21172224ull;

  detect_kernel<<<1, 256, 0, stream>>>(pts, flag, dstats);
  fps_kernel<<<NB, 256, 0, stream>>>(pts, centw, d_out, flag);
  if (ft) transpose_kernel<<<NB*NPT/256, 256, 0, stream>>>(feats, ftp, flag);
  ballq_kernel<<<NB*MC/4, 256, 0, stream>>>(pts, centw, gidx, flag);

  const int fti = ft ? 1 : 0;
  const int GRID = NB*MC/8;
  mlp_kernel<1,true ><<<GRID, 256, 0, stream>>>(pts,feats,ftp,fti,w1,b1,w2,b2,w3,b3,centw,gidx,dstats,fstats,d_out,flag);
  mlp_kernel<1,false><<<GRID, 256, 0, stream>>>(pts,feats,ftp,fti,w1,b1,w2,b2,w3,b3,centw,gidx,dstats,fstats,d_out,flag);
  finalize_kernel<<<1, 64, 0, stream>>>(dstats, fstats, g1, be1, flag, 1);
  mlp_kernel<2,true ><<<GRID, 256, 0, stream>>>(pts,feats,ftp,fti,w1,b1,w2,b2,w3,b3,centw,gidx,dstats,fstats,d_out,flag);
  mlp_kernel<2,false><<<GRID, 256, 0, stream>>>(pts,feats,ftp,fti,w1,b1,w2,b2,w3,b3,centw,gidx,dstats,fstats,d_out,flag);
  finalize_kernel<<<1, 64, 0, stream>>>(dstats, fstats, g2, be2, flag, 2);
  mlp_kernel<3,true ><<<GRID, 256, 0, stream>>>(pts,feats,ftp,fti,w1,b1,w2,b2,w3,b3,centw,gidx,dstats,fstats,d_out,flag);
  mlp_kernel<3,false><<<GRID, 256, 0, stream>>>(pts,feats,ftp,fti,w1,b1,w2,b2,w3,b3,centw,gidx,dstats,fstats,d_out,flag);
}